// Round 5
// baseline (288.553 us; speedup 1.0000x reference)
//
#include <hip/hip_runtime.h>
#include <math.h>

typedef __attribute__((ext_vector_type(8))) short short8v;
typedef __attribute__((ext_vector_type(4))) float float4v;

static __device__ __forceinline__ unsigned short f2bf(float f) {
  union { float f; unsigned int u; } v; v.f = f;
  unsigned int r = v.u + 0x7fffu + ((v.u >> 16) & 1u);
  return (unsigned short)(r >> 16);
}
static __device__ __forceinline__ float bf2f(unsigned short h) {
  union { unsigned int u; float f; } v; v.u = ((unsigned int)h) << 16;
  return v.f;
}
static __device__ __forceinline__ void wave_fence() {
  asm volatile("s_waitcnt lgkmcnt(0)" ::: "memory");
}

// ---------------- K1: KNN via bitonic selection ----------------
__global__ __launch_bounds__(512) void k_knn(const float* __restrict__ x,
                                             float* __restrict__ rec,
                                             int*   __restrict__ idxArr,
                                             float* __restrict__ mmPart) {
  __shared__ float px[2048], py[2048], pz[2048];
  __shared__ unsigned long long listK[8][64];
  __shared__ float wmn[8], wmx[8];

  const int b = blockIdx.y;
  const int t = threadIdx.x;
  const float* xb = x + (size_t)b * 3 * 2048;
  for (int i = t; i < 2048; i += 512) {
    px[i] = xb[i];
    py[i] = xb[2048 + i];
    pz[i] = xb[4096 + i];
  }
  __syncthreads();

  const int w = t >> 6, lane = t & 63;
  const int n = blockIdx.x * 8 + w;
  const float sx = px[n], sy = py[n], sz = pz[n];

  float lmin = 1e30f;
  for (int j = lane; j < 2048; j += 64) {
    float dx = px[j] - sx, dy = py[j] - sy, dz = pz[j] - sz;
    float d = fmaf(dx, dx, fmaf(dy, dy, dz * dz));
    lmin = fminf(lmin, d);
  }
  unsigned k32 = __float_as_uint(lmin);
  #pragma unroll
  for (int kk = 2; kk <= 64; kk <<= 1) {
    #pragma unroll
    for (int jj = kk >> 1; jj > 0; jj >>= 1) {
      unsigned o = __shfl_xor(k32, jj);
      bool keepMin = (((lane & jj) == 0) == ((lane & kk) == 0));
      unsigned mn = k32 < o ? k32 : o;
      unsigned mx = k32 < o ? o : k32;
      k32 = keepMin ? mn : mx;
    }
  }
  const float T = __uint_as_float(__shfl(k32, 19));

  int base = 0;
  for (int j = lane; j < 2048; j += 64) {
    float dx = px[j] - sx, dy = py[j] - sy, dz = pz[j] - sz;
    float d = fmaf(dx, dx, fmaf(dy, dy, dz * dz));
    bool hit = (d <= T);
    unsigned long long mask = __ballot(hit);
    if (hit) {
      int slot = base + __popcll(mask & ((1ull << lane) - 1ull));
      if (slot < 64)
        listK[w][slot] = (((unsigned long long)__float_as_uint(d)) << 32) | (unsigned)j;
    }
    base += __popcll(mask);
  }
  const int M = base;

  float myD = 0.f; int myJ = 0;
  if (M > 64) {
    float lastD = -1.f; int lastJ = -1;
    for (int r = 0; r < 20; ++r) {
      float bd = 1e30f; int bj = 0x7fffffff;
      for (int j = lane; j < 2048; j += 64) {
        float dx = px[j] - sx, dy = py[j] - sy, dz = pz[j] - sz;
        float d = fmaf(dx, dx, fmaf(dy, dy, dz * dz));
        bool valid = (d > lastD) || (d == lastD && j > lastJ);
        if (valid && (d < bd || (d == bd && j < bj))) { bd = d; bj = j; }
      }
      for (int s = 1; s < 64; s <<= 1) {
        float od = __shfl_xor(bd, s); int oj = __shfl_xor(bj, s);
        if (od < bd || (od == bd && oj < bj)) { bd = od; bj = oj; }
      }
      if (lane == r) { myD = bd; myJ = bj; }
      lastD = bd; lastJ = bj;
    }
  } else {
    wave_fence();
    unsigned long long key = (lane < M) ? listK[w][lane] : 0xFFFFFFFFFFFFFFFFull;
    #pragma unroll
    for (int kk = 2; kk <= 64; kk <<= 1) {
      #pragma unroll
      for (int jj = kk >> 1; jj > 0; jj >>= 1) {
        unsigned long long o = __shfl_xor(key, jj);
        bool keepMin = (((lane & jj) == 0) == ((lane & kk) == 0));
        unsigned long long mn = key < o ? key : o;
        unsigned long long mx = key < o ? o : key;
        key = keepMin ? mn : mx;
      }
    }
    myD = __uint_as_float((unsigned)(key >> 32));
    myJ = (int)(unsigned)(key & 0xFFFFFFFFu);
  }

  float row_mn = 1e30f, row_mx = -1e30f;
  const size_t row = (size_t)b * 2048 + n;
  if (lane < 20) {
    int j = myJ;
    idxArr[row * 20 + lane] = j;
    float rx = px[j] - sx, ry = py[j] - sy, rz = pz[j] - sz;
    float dis = sqrtf(myD);
    float* rp = rec + row * 88;
    rp[4 + lane]  = dis;
    rp[24 + lane] = rx;
    rp[44 + lane] = ry;
    rp[64 + lane] = rz;
    row_mn = fminf(fminf(rx, ry), fminf(rz, dis));
    row_mx = fmaxf(fmaxf(rx, ry), fmaxf(rz, dis));
    if (lane == 0) {
      rp[0] = sx; rp[1] = sy; rp[2] = sz; rp[3] = 0.f;
      row_mn = fminf(row_mn, fminf(fminf(sx, sy), sz));
      row_mx = fmaxf(row_mx, fmaxf(fmaxf(sx, sy), sz));
    }
  }
  for (int s = 1; s < 64; s <<= 1) {
    row_mn = fminf(row_mn, __shfl_xor(row_mn, s));
    row_mx = fmaxf(row_mx, __shfl_xor(row_mx, s));
  }
  if (lane == 0) { wmn[w] = row_mn; wmx[w] = row_mx; }
  __syncthreads();
  if (t == 0) {
    float mn = wmn[0], mx = wmx[0];
    #pragma unroll
    for (int i = 1; i < 8; ++i) { mn = fminf(mn, wmn[i]); mx = fmaxf(mx, wmx[i]); }
    int bid = blockIdx.y * 256 + blockIdx.x;
    mmPart[bid * 2]     = mn;
    mmPart[bid * 2 + 1] = mx;
  }
}

// ---------------- K1b: minmax reduce, M matrix, bf16 weight prep ----------------
__global__ __launch_bounds__(256) void k_prep(const float* __restrict__ A,
                                              const float* __restrict__ kern,
                                              const float* __restrict__ W1,
                                              const float* __restrict__ Wmlp,
                                              const float* __restrict__ mmPart,
                                              float* __restrict__ scal,
                                              unsigned short* __restrict__ W1Bg,
                                              unsigned short* __restrict__ WmBg) {
  __shared__ float smn[256], smx[256];
  const int t = threadIdx.x;
  float mn = 1e30f, mx = -1e30f;
  for (int i = t; i < 4096; i += 256) {
    mn = fminf(mn, mmPart[i * 2]);
    mx = fmaxf(mx, mmPart[i * 2 + 1]);
  }
  smn[t] = mn; smx[t] = mx;
  __syncthreads();
  for (int s = 128; s > 0; s >>= 1) {
    if (t < s) { smn[t] = fminf(smn[t], smn[t + s]); smx[t] = fmaxf(smx[t], smx[t + s]); }
    __syncthreads();
  }
  if (t == 0) scal[0] = smn[0] / (smx[0] - smn[0]);   // c  (ref precedence: x - mn/(mx-mn))
  if (t < 24) {
    int d = t >> 3, e = t & 7;
    float s = 0.f;
    for (int d2 = 0; d2 < 3; ++d2)
      s += 0.5f * (A[d * 3 + d2] + A[d2 * 3 + d]) * kern[d2 * 8 + e];
    scal[1 + t] = s;
  }
  // W1B[o][u] = bf16(W1[o][(u%48)*4 + u/48])  (feats group-shuffle folded in)
  for (int i = t; i < 12288; i += 256) {
    int o = i / 192, u = i % 192;
    int g = u / 48, r = u % 48;
    W1Bg[i] = f2bf(W1[o * 192 + r * 4 + g]);
  }
  for (int i = t; i < 2048; i += 256) WmBg[i] = f2bf(Wmlp[i]);
}

// ---------------- K2: transpose feature (B,64,N) -> featN (B,N,64) ----------------
__global__ __launch_bounds__(256) void k_transpose(const float* __restrict__ f,
                                                   float* __restrict__ fN) {
  __shared__ float tile[64][65];
  const int b = blockIdx.y, n0 = blockIdx.x * 64, t = threadIdx.x;
  const float* fb = f + (size_t)b * 64 * 2048;
  for (int i = t; i < 4096; i += 256) {
    int c = i >> 6, nl = i & 63;
    tile[c][nl] = fb[c * 2048 + n0 + nl];
  }
  __syncthreads();
  float* out = fN + ((size_t)b * 2048 + n0) * 64;
  for (int i = t; i < 4096; i += 256) {
    int nl = i >> 6, c = i & 63;
    out[nl * 64 + c] = tile[c][nl];
  }
}

// ---------------- K3: main, wave-per-point + MFMA, 1 barrier, 4 blocks/CU ----------------
// LDS: ffb 11520 + aggB 12800 + xmLb 5632 + permL 2560 + recL 1536
//      + selfFL 1024 + f0L 1024 + colsumL 128 = 38224 B
__global__ __launch_bounds__(256, 4) void k_main(const float* __restrict__ rec,
    const int* __restrict__ idxArr, const float* __restrict__ featN,
    const float* __restrict__ scal, const unsigned short* __restrict__ W1Bg,
    const unsigned short* __restrict__ WmBg, const float* __restrict__ Bf,
    const float* __restrict__ onePad, const float* __restrict__ bmlp,
    const float* __restrict__ b1, const float* __restrict__ Wout,
    float* __restrict__ hT) {
  __shared__ __align__(16) unsigned short ffb[4][20 * 72]; // per-wave Fourier bf16 (stride 72)
  __shared__ __align__(16) unsigned short aggB[32 * 200];  // block-wide h-MFMA A-matrix
  __shared__ __align__(16) unsigned short xmLb[4][32 * 22];
  __shared__ float permL[4][160];
  __shared__ float recL[4][96];
  __shared__ float selfFL[4][64];
  __shared__ float f0L[4][64];
  __shared__ float colsumL[4][8];

  const int t = threadIdx.x;
  const int pt = t >> 6, lane = t & 63;
  const int row = blockIdx.x * 4 + pt;
  const int b = row >> 11;

  // ---- per-wave loads; issue all gathers early ----
  recL[pt][lane] = rec[(size_t)row * 88 + lane];
  if (lane < 24) recL[pt][64 + lane] = rec[(size_t)row * 88 + 64 + lane];
  selfFL[pt][lane] = featN[(size_t)row * 64 + lane];
  int myidx = 0;
  if (lane < 20) myidx = idxArr[(size_t)row * 20 + lane];
  float gv[20];
  {
    const float* fNb = featN + (((size_t)b << 11) * 64);
    #pragma unroll
    for (int k = 0; k < 20; ++k) {
      int j = __shfl(myidx, k);
      gv[k] = fNb[(size_t)j * 64 + lane];
    }
  }

  // per-lane constants
  const int m31 = lane & 31;
  float bf_[7];
  #pragma unroll
  for (int d = 0; d < 7; ++d) bf_[d] = Bf[d * 32 + m31];
  const float c0 = scal[0];
  const int e7 = lane & 7;
  const float M0 = scal[1 + e7], M1 = scal[9 + e7], M2 = scal[17 + e7];
  const float bm0 = bmlp[lane & 15], bm1 = bmlp[16 + (lane & 15)];
  wave_fence();

  // ---- Fourier features -> ffb rows 0..19 (bf16, stride 72) ----
  {
    const float rpx = recL[pt][0] - c0, rpy = recL[pt][1] - c0, rpz = recL[pt][2] - c0;
    const float basev = rpx * bf_[0] + rpy * bf_[1] + rpz * bf_[2];
    const int khalf = lane >> 5;
    #pragma unroll
    for (int it = 0; it < 10; ++it) {
      int k = khalf + 2 * it;
      float dis = recL[pt][4 + k] - c0;
      float rx  = recL[pt][24 + k] - c0;
      float ry  = recL[pt][44 + k] - c0;
      float rz  = recL[pt][64 + k] - c0;
      float s = basev + rx * bf_[3] + ry * bf_[4] + rz * bf_[5] + dis * bf_[6];
      float th = 6.283185307179586f * s;
      float sv, cv; __sincosf(th, &sv, &cv);
      ffb[pt][k * 72 + m31]      = f2bf(sv);
      ffb[pt][k * 72 + 32 + m31] = f2bf(cv);
    }
  }

  // ---- perm logits ----
  #pragma unroll
  for (int it = 0; it < 3; ++it) {
    int i = lane + 64 * it;
    if (i < 160) {
      int k = i >> 3;
      float v = recL[pt][24 + k] * M0 + recL[pt][44 + k] * M1
              + recL[pt][64 + k] * M2 + onePad[k * 8 + e7];
      permL[pt][k * 8 + e7] = v;
    }
  }
  wave_fence();

  // ---- topkmax softmax over k (8 lanes) ----
  if (lane < 8) {
    float mx = -1e30f;
    #pragma unroll
    for (int k = 0; k < 20; ++k) mx = fmaxf(mx, permL[pt][k * 8 + lane]);
    float s1 = 0.f;
    #pragma unroll
    for (int k = 0; k < 20; ++k) s1 += __expf(permL[pt][k * 8 + lane] - mx);
    float inv = 1.f / s1, s2 = 0.f;
    #pragma unroll
    for (int k = 0; k < 20; ++k) {
      float q = __expf(permL[pt][k * 8 + lane] - mx) * inv;
      if (q > 0.05f) s2 += q;
    }
    float inv2 = 1.f / (s2 + 1e-6f);
    #pragma unroll
    for (int k = 0; k < 20; ++k) {
      float q = __expf(permL[pt][k * 8 + lane] - mx) * inv;
      q = (q > 0.05f) ? q : 0.f;
      permL[pt][k * 8 + lane] = q * inv2;
    }
    colsumL[pt][lane] = s2 * inv2;
  }
  wave_fence();

  // ---- x_mlp via MFMA: tile0 = ff rows 0..15, tile1 = ff rows 4..19 (overlap) ----
  const int fr = lane & 15, fg = lane >> 4;
  {
    float4v acc00 = float4v{bm0, bm0, bm0, bm0};
    float4v acc01 = float4v{bm1, bm1, bm1, bm1};
    float4v acc10 = float4v{bm0, bm0, bm0, bm0};
    float4v acc11 = float4v{bm1, bm1, bm1, bm1};
    #pragma unroll
    for (int ks = 0; ks < 2; ++ks) {
      short8v a0 = *(const short8v*)&ffb[pt][fr * 72 + ks * 32 + fg * 8];
      short8v a1 = *(const short8v*)&ffb[pt][(4 + fr) * 72 + ks * 32 + fg * 8];
      short8v b0 = *(const short8v*)(WmBg + fr * 64 + ks * 32 + fg * 8);
      short8v b1v = *(const short8v*)(WmBg + (16 + fr) * 64 + ks * 32 + fg * 8);
      acc00 = __builtin_amdgcn_mfma_f32_16x16x32_bf16(a0, b0,  acc00, 0, 0, 0);
      acc01 = __builtin_amdgcn_mfma_f32_16x16x32_bf16(a0, b1v, acc01, 0, 0, 0);
      acc10 = __builtin_amdgcn_mfma_f32_16x16x32_bf16(a1, b0,  acc10, 0, 0, 0);
      acc11 = __builtin_amdgcn_mfma_f32_16x16x32_bf16(a1, b1v, acc11, 0, 0, 0);
    }
    // D row = fg*4+rg; tile0 -> kk = 4*fg+rg (0..15); tile1 -> kk = 4+4*fg+rg, keep fg==3 (16..19)
    #pragma unroll
    for (int rg = 0; rg < 4; ++rg) {
      int kk0 = 4 * fg + rg;
      xmLb[pt][fr * 22 + kk0]        = f2bf(acc00[rg]);
      xmLb[pt][(16 + fr) * 22 + kk0] = f2bf(acc01[rg]);
    }
    if (fg == 3) {
      #pragma unroll
      for (int rg = 0; rg < 4; ++rg) {
        int kk1 = 16 + rg;
        xmLb[pt][fr * 22 + kk1]        = f2bf(acc10[rg]);
        xmLb[pt][(16 + fr) * 22 + kk1] = f2bf(acc11[rg]);
      }
    }
  }
  wave_fence();

  // ---- aggregation -> aggB rows pt*8+e (block-wide, no aliasing) ----
  float cs[8];
  {
    float4v c01 = *(const float4v*)&colsumL[pt][0];
    float4v c23 = *(const float4v*)&colsumL[pt][4];
    cs[0] = c01[0]; cs[1] = c01[1]; cs[2] = c01[2]; cs[3] = c01[3];
    cs[4] = c23[0]; cs[5] = c23[1]; cs[6] = c23[2]; cs[7] = c23[3];
  }
  {
    float acc[8];
    #pragma unroll
    for (int e = 0; e < 8; ++e) acc[e] = 0.f;
    #pragma unroll
    for (int k = 0; k < 20; ++k) {
      float v = gv[k];
      float4v p0 = *(const float4v*)&permL[pt][k * 8];
      float4v p1 = *(const float4v*)&permL[pt][k * 8 + 4];
      acc[0] = fmaf(v, p0[0], acc[0]); acc[1] = fmaf(v, p0[1], acc[1]);
      acc[2] = fmaf(v, p0[2], acc[2]); acc[3] = fmaf(v, p0[3], acc[3]);
      acc[4] = fmaf(v, p1[0], acc[4]); acc[5] = fmaf(v, p1[1], acc[5]);
      acc[6] = fmaf(v, p1[2], acc[6]); acc[7] = fmaf(v, p1[3], acc[7]);
    }
    float f0 = gv[0];
    f0L[pt][lane] = f0;
    #pragma unroll
    for (int e = 0; e < 8; ++e) {
      float repv = f0 * cs[e];
      aggB[(pt * 8 + e) * 200 + lane]      = f2bf(repv);           // u: f_neigh rep
      aggB[(pt * 8 + e) * 200 + 96 + lane] = f2bf(acc[e] - repv);  // u: f_neigh diff
    }
  }
  {
    const int o2 = lane & 31, hf = lane >> 5;
    float accX[8];
    #pragma unroll
    for (int e = 0; e < 8; ++e) accX[e] = 0.f;
    #pragma unroll
    for (int kk = 0; kk < 10; ++kk) {
      int k = hf * 10 + kk;
      float xv = bf2f(xmLb[pt][o2 * 22 + k]);
      float4v p0 = *(const float4v*)&permL[pt][k * 8];
      float4v p1 = *(const float4v*)&permL[pt][k * 8 + 4];
      accX[0] = fmaf(xv, p0[0], accX[0]); accX[1] = fmaf(xv, p0[1], accX[1]);
      accX[2] = fmaf(xv, p0[2], accX[2]); accX[3] = fmaf(xv, p0[3], accX[3]);
      accX[4] = fmaf(xv, p1[0], accX[4]); accX[5] = fmaf(xv, p1[1], accX[5]);
      accX[6] = fmaf(xv, p1[2], accX[6]); accX[7] = fmaf(xv, p1[3], accX[7]);
    }
    #pragma unroll
    for (int e = 0; e < 8; ++e) accX[e] += __shfl_xor(accX[e], 32);
    float xm0 = bf2f(xmLb[pt][o2 * 22]);
    if (hf == 0) {
      #pragma unroll
      for (int e = 0; e < 8; ++e)
        aggB[(pt * 8 + e) * 200 + 64 + o2] = f2bf(xm0 * cs[e]);             // u: x_mlp rep
    } else {
      #pragma unroll
      for (int e = 0; e < 8; ++e)
        aggB[(pt * 8 + e) * 200 + 160 + o2] = f2bf(accX[e] - xm0 * cs[e]);  // u: x_mlp diff
    }
  }
  __syncthreads();

  // ---- h-stage MFMA: (32 rows x 192) @ W1B^T(192 x 64) ----
  const int mt = pt & 1, ntb = (pt >> 1) * 2;
  float4v h0 = float4v{0.f, 0.f, 0.f, 0.f};
  float4v h1 = float4v{0.f, 0.f, 0.f, 0.f};
  {
    const unsigned short* aRow = &aggB[(mt * 16 + fr) * 200];
    const unsigned short* w1p0 = W1Bg + ((ntb * 16 + fr) * 192);
    const unsigned short* w1p1 = W1Bg + (((ntb + 1) * 16 + fr) * 192);
    #pragma unroll
    for (int ks = 0; ks < 6; ++ks) {
      short8v a  = *(const short8v*)(aRow + ks * 32 + fg * 8);
      short8v b0 = *(const short8v*)(w1p0 + ks * 32 + fg * 8);
      short8v b1v = *(const short8v*)(w1p1 + ks * 32 + fg * 8);
      h0 = __builtin_amdgcn_mfma_f32_16x16x32_bf16(a, b0,  h0, 0, 0, 0);
      h1 = __builtin_amdgcn_mfma_f32_16x16x32_bf16(a, b1v, h1, 0, 0, 0);
    }
  }

  // ---- post, in-register: max over e, +b1, gelu, residual, store ----
  {
    float m0 = fmaxf(fmaxf(h0[0], h0[1]), fmaxf(h0[2], h0[3]));
    float m1 = fmaxf(fmaxf(h1[0], h1[1]), fmaxf(h1[2], h1[3]));
    m0 = fmaxf(m0, __shfl_xor(m0, 16));
    m1 = fmaxf(m1, __shfl_xor(m1, 16));
    const int p_loc = 2 * mt + (fg >> 1);
    const int col = (ntb + (fg & 1)) * 16 + fr;
    float hm = ((fg & 1) ? m1 : m0) + b1[col];
    float g = 0.5f * hm * (1.f + erff(hm * 0.7071067811865476f));
    float res = 0.f;
    const float* wr = Wout + col * 64;
    #pragma unroll
    for (int c = 0; c < 64; c += 4) {
      float4 wv = *(const float4*)(wr + c);
      res = fmaf(wv.x, selfFL[p_loc][c],     res);
      res = fmaf(wv.y, selfFL[p_loc][c + 1], res);
      res = fmaf(wv.z, selfFL[p_loc][c + 2], res);
      res = fmaf(wv.w, selfFL[p_loc][c + 3], res);
    }
    hT[(size_t)(blockIdx.x * 4 + p_loc) * 64 + col] = g + res;
  }
  (void)f0L;
}

// ---------------- K4: BN statistics (deterministic two-stage) ----------------
__global__ __launch_bounds__(256) void k_bnstat(const float* __restrict__ hT,
                                                float* __restrict__ part) {
  const int bk = blockIdx.x;
  const int t = threadIdx.x;
  const int o = t & 63, rg = t >> 6;
  float s = 0.f, s2 = 0.f;
  for (int r = bk * 512 + rg; r < (bk + 1) * 512; r += 4) {
    float v = hT[(size_t)r * 64 + o];
    s += v;
    s2 = fmaf(v, v, s2);
  }
  __shared__ float ls[256], ls2[256];
  ls[t] = s; ls2[t] = s2;
  __syncthreads();
  if (t < 64) {
    float a  = ls[t] + ls[t + 64] + ls[t + 128] + ls[t + 192];
    float a2 = ls2[t] + ls2[t + 64] + ls2[t + 128] + ls2[t + 192];
    part[(bk * 64 + t) * 2]     = a;
    part[(bk * 64 + t) * 2 + 1] = a2;
  }
}

__global__ void k_bnfinal(const float* __restrict__ part, float* __restrict__ stats) {
  const int t = threadIdx.x;
  if (t < 64) {
    float s = 0.f, s2 = 0.f;
    for (int bk = 0; bk < 64; ++bk) {
      s  += part[(bk * 64 + t) * 2];
      s2 += part[(bk * 64 + t) * 2 + 1];
    }
    float mu  = s * (1.f / 32768.f);
    float var = s2 * (1.f / 32768.f) - mu * mu;
    stats[t * 2]     = mu;
    stats[t * 2 + 1] = 1.f / sqrtf(var + 1e-5f);
  }
}

// ---------------- K5: BN apply + transpose to (B,64,N) ----------------
__global__ __launch_bounds__(256) void k_bnapply(const float* __restrict__ hT,
                                                 const float* __restrict__ stats,
                                                 const float* __restrict__ gamma,
                                                 const float* __restrict__ beta,
                                                 float* __restrict__ out) {
  __shared__ float tile[64][65];
  __shared__ float sMu[64], sRs[64], sGa[64], sBe[64];
  const int t = threadIdx.x;
  const int r0 = blockIdx.x * 64;
  if (t < 64) {
    sMu[t] = stats[t * 2];
    sRs[t] = stats[t * 2 + 1];
    sGa[t] = gamma[t];
    sBe[t] = beta[t];
  }
  __syncthreads();
  for (int i = t; i < 4096; i += 256) {
    int rl = i >> 6, o = i & 63;
    float v = hT[(size_t)(r0 + rl) * 64 + o];
    tile[rl][o] = fmaf((v - sMu[o]) * sRs[o], sGa[o], sBe[o]);
  }
  __syncthreads();
  const int b = r0 >> 11, n0 = r0 & 2047;
  for (int i = t; i < 4096; i += 256) {
    int o = i >> 6, nl = i & 63;
    out[((size_t)b * 64 + o) * 2048 + n0 + nl] = tile[nl][o];
  }
}

// ---------------- launch ----------------
extern "C" void kernel_launch(void* const* d_in, const int* in_sizes, int n_in,
                              void* d_out, int out_size, void* d_ws, size_t ws_size,
                              hipStream_t stream) {
  const float* x       = (const float*)d_in[0];
  const float* feature = (const float*)d_in[1];
  const float* A       = (const float*)d_in[2];
  const float* Bf      = (const float*)d_in[3];
  const float* kern    = (const float*)d_in[4];
  const float* onePad  = (const float*)d_in[5];
  const float* Wmlp    = (const float*)d_in[6];
  const float* bmlp    = (const float*)d_in[7];
  const float* W1      = (const float*)d_in[8];
  const float* b1      = (const float*)d_in[9];
  const float* gamma   = (const float*)d_in[10];
  const float* beta    = (const float*)d_in[11];
  const float* Wout    = (const float*)d_in[12];

  char* ws = (char*)d_ws;
  float* rec             = (float*)(ws);                     // 11,534,336
  int*   idxA            = (int*)  (ws + 11534336);          // -> 14,155,776
  float* featN           = (float*)(ws + 14155776);          // -> 22,544,384
  float* hT              = (float*)(ws + 22544384);          // -> 30,932,992
  unsigned short* W1Bg   = (unsigned short*)(ws + 30932992); // -> 30,957,568
  unsigned short* WmBg   = (unsigned short*)(ws + 30957568); // -> 30,961,664
  float* mmPart          = (float*)(ws + 30961664);          // -> 30,994,432
  float* scal            = (float*)(ws + 30994432);          // -> 30,994,688
  float* bnPart          = (float*)(ws + 30994688);          // -> 31,027,456
  float* bnStats         = (float*)(ws + 31027456);          // -> 31,027,968

  k_knn<<<dim3(256, 16), 512, 0, stream>>>(x, rec, idxA, mmPart);
  k_prep<<<1, 256, 0, stream>>>(A, kern, W1, Wmlp, mmPart, scal, W1Bg, WmBg);
  k_transpose<<<dim3(32, 16), 256, 0, stream>>>(feature, featN);
  k_main<<<8192, 256, 0, stream>>>(rec, idxA, featN, scal, W1Bg, WmBg,
                                   Bf, onePad, bmlp, b1, Wout, hT);
  k_bnstat<<<64, 256, 0, stream>>>(hT, bnPart);
  k_bnfinal<<<1, 64, 0, stream>>>(bnPart, bnStats);
  k_bnapply<<<512, 256, 0, stream>>>(hT, bnStats, gamma, beta, (float*)d_out);
}